// Round 2
// baseline (468.126 us; speedup 1.0000x reference)
//
#include <hip/hip_runtime.h>

#define ALPHA 0.2f
#define NODE_BLOCKS 2048
#define EDGE_BLOCKS 512

// Fused: per-block tiny precompute (from L2-cached weights) + attention
// exp-values + atomic segment sums. Blocks [0, NODE_BLOCKS) do node rows,
// the rest do edge rows.
//
// cst layout (LDS): [0..63] w_n = W_node @ a_node[64:], [64..79] w_e =
// W_edge @ a_edge[64:], [80] c_node = g_v . a_node[:64], [81] c_edge.
__global__ __launch_bounds__(256)
void ga_att_fused(const float* __restrict__ node_fts,
                  const float* __restrict__ edges,
                  const float* __restrict__ graph_fts,
                  const int* __restrict__ seg_ids,
                  const float* __restrict__ W_node,
                  const float* __restrict__ W_edge,
                  const float* __restrict__ W_graph,
                  const float* __restrict__ a_node,
                  const float* __restrict__ a_edge,
                  float* __restrict__ out,        // [2N]: e_node | e_edge
                  float* __restrict__ sums_node,  // ws, zeroed
                  float* __restrict__ sums_edge,  // ws, zeroed
                  int N, int E) {
    __shared__ __align__(16) float cst[84];
    const int t = threadIdx.x;

    if (t < 64) {  // wave 0 computes the tiny precompute
        float g = 0.f;
        #pragma unroll
        for (int c = 0; c < 32; ++c) g += graph_fts[c] * W_graph[c * 64 + t];

        float wn = 0.f;
        #pragma unroll
        for (int c = 0; c < 64; ++c) wn += W_node[t * 64 + c] * a_node[64 + c];
        cst[t] = wn;

        if (t < 16) {
            float we = 0.f;
            #pragma unroll
            for (int c = 0; c < 64; ++c) we += W_edge[t * 64 + c] * a_edge[64 + c];
            cst[64 + t] = we;
        }
        float cn = g * a_node[t];
        float ce = g * a_edge[t];
        #pragma unroll
        for (int off = 32; off > 0; off >>= 1) {
            cn += __shfl_down(cn, off);
            ce += __shfl_down(ce, off);
        }
        if (t == 0) { cst[80] = cn; cst[81] = ce; }
    }
    __syncthreads();

    if (blockIdx.x < NODE_BLOCKS) {
        // 16 lanes per node row (64 f32); wave covers 4 rows = 1 KiB contiguous
        const int lane16 = t & 15;
        const float4 w = *reinterpret_cast<const float4*>(&cst[lane16 * 4]);
        const float c_node = cst[80];
        const int group = ((blockIdx.x << 8) + t) >> 4;
        const int ngroups = (NODE_BLOCKS << 8) >> 4;
        for (int row = group; row < N; row += ngroups) {
            const float4 x = *reinterpret_cast<const float4*>(
                &node_fts[(size_t)row * 64 + lane16 * 4]);
            float d = x.x * w.x + x.y * w.y + x.z * w.z + x.w * w.w;
            d += __shfl_xor(d, 1);
            d += __shfl_xor(d, 2);
            d += __shfl_xor(d, 4);
            d += __shfl_xor(d, 8);
            if (lane16 == 0) {
                float att = c_node + d;
                att = att > 0.f ? att : ALPHA * att;
                att = fminf(fmaxf(att, -2.f), 2.f);
                const float e = expf(att);
                out[row] = e;
                atomicAdd(&sums_node[seg_ids[row]], e);
            }
        }
    } else {
        // 4 lanes per edge row (16 f32); wave covers 16 rows = 1 KiB contiguous
        const int lane4 = t & 3;
        const float4 w = *reinterpret_cast<const float4*>(&cst[64 + lane4 * 4]);
        const float c_edge = cst[81];
        const int bid = blockIdx.x - NODE_BLOCKS;
        const int group = ((bid << 8) + t) >> 2;
        const int ngroups = (EDGE_BLOCKS << 8) >> 2;
        for (int row = group; row < E; row += ngroups) {
            const float4 x = *reinterpret_cast<const float4*>(
                &edges[(size_t)row * 16 + lane4 * 4]);
            float d = x.x * w.x + x.y * w.y + x.z * w.z + x.w * w.w;
            d += __shfl_xor(d, 1);
            d += __shfl_xor(d, 2);
            if (lane4 == 0) {
                float att = c_edge + d;
                att = att > 0.f ? att : ALPHA * att;
                att = fminf(fmaxf(att, -2.f), 2.f);
                const float e = expf(att);
                out[N + row] = e;
                atomicAdd(&sums_edge[seg_ids[row]], e);
            }
        }
    }
}

// Normalize both halves in place; vectorized 4 rows/thread.
__global__ __launch_bounds__(256)
void ga_norm_kernel(const int* __restrict__ seg_ids,
                    const float* __restrict__ sums_node,
                    const float* __restrict__ sums_edge,
                    float* __restrict__ out, int N) {
    const int idx = blockIdx.x * blockDim.x + threadIdx.x;
    const int stride = gridDim.x * blockDim.x;
    if ((N & 3) == 0) {
        const int n4 = N >> 2;
        float* out2 = out + N;
        for (int q = idx; q < n4; q += stride) {
            const int4 s = reinterpret_cast<const int4*>(seg_ids)[q];
            float4 o1 = reinterpret_cast<float4*>(out)[q];
            float4 o2 = reinterpret_cast<float4*>(out2)[q];
            o1.x /= sums_node[s.x]; o1.y /= sums_node[s.y];
            o1.z /= sums_node[s.z]; o1.w /= sums_node[s.w];
            o2.x /= sums_edge[s.x]; o2.y /= sums_edge[s.y];
            o2.z /= sums_edge[s.z]; o2.w /= sums_edge[s.w];
            reinterpret_cast<float4*>(out)[q] = o1;
            reinterpret_cast<float4*>(out2)[q] = o2;
        }
    } else {
        for (int j = idx; j < N; j += stride) {
            const int s = seg_ids[j];
            out[j]     /= sums_node[s];
            out[N + j] /= sums_edge[s];
        }
    }
}

extern "C" void kernel_launch(void* const* d_in, const int* in_sizes, int n_in,
                              void* d_out, int out_size, void* d_ws, size_t ws_size,
                              hipStream_t stream) {
    const float* node_fts  = (const float*)d_in[0];
    // d_in[1] (edge_fts) is unused by the reference computation.
    const float* graph_fts = (const float*)d_in[2];
    const float* edges     = (const float*)d_in[3];
    const int*   seg_ids   = (const int*)  d_in[4];
    const float* W_node    = (const float*)d_in[5];
    const float* W_edge    = (const float*)d_in[6];
    const float* W_graph   = (const float*)d_in[7];
    const float* a_node    = (const float*)d_in[8];
    const float* a_edge    = (const float*)d_in[9];

    const int N = in_sizes[0] / 64;   // node rows
    const int E = in_sizes[4];        // edge rows == seg_ids count

    float* out       = (float*)d_out;
    float* sums_node = (float*)d_ws;        // [N]
    float* sums_edge = sums_node + N;       // [N]

    hipMemsetAsync(d_ws, 0, (size_t)(2 * N) * sizeof(float), stream);

    ga_att_fused<<<NODE_BLOCKS + EDGE_BLOCKS, 256, 0, stream>>>(
        node_fts, edges, graph_fts, seg_ids, W_node, W_edge, W_graph,
        a_node, a_edge, out, sums_node, sums_edge, N, E);

    ga_norm_kernel<<<1024, 256, 0, stream>>>(seg_ids, sums_node, sums_edge,
                                             out, N);
}

// Round 5
// 442.875 us; speedup vs baseline: 1.0570x; 1.0570x over previous
//
#include <hip/hip_runtime.h>

#define ALPHA 0.2f

// consts layout in ws (after the two sum arrays):
//   [0..63]  w_n   = W_node @ a_node[64:128]
//   [64..79] w_e   = W_edge @ a_edge[64:128]
//   [80]     c_node = (graph_fts@W_graph) . a_node[0:64]
//   [81]     c_edge = (graph_fts@W_graph) . a_edge[0:64]
__global__ void ga_consts_kernel(const float* __restrict__ graph_fts,
                                 const float* __restrict__ W_node,
                                 const float* __restrict__ W_edge,
                                 const float* __restrict__ W_graph,
                                 const float* __restrict__ a_node,
                                 const float* __restrict__ a_edge,
                                 float* __restrict__ consts) {
    const int k = threadIdx.x;  // 0..63, one wave

    float g = 0.f;
    #pragma unroll
    for (int c = 0; c < 32; ++c) g += graph_fts[c] * W_graph[c * 64 + k];

    float wn = 0.f;
    #pragma unroll
    for (int c = 0; c < 64; ++c) wn += W_node[k * 64 + c] * a_node[64 + c];
    consts[k] = wn;

    if (k < 16) {
        float we = 0.f;
        #pragma unroll
        for (int c = 0; c < 64; ++c) we += W_edge[k * 64 + c] * a_edge[64 + c];
        consts[64 + k] = we;
    }

    float cn = g * a_node[k];
    float ce = g * a_edge[k];
    #pragma unroll
    for (int off = 32; off > 0; off >>= 1) {
        cn += __shfl_down(cn, off);
        ce += __shfl_down(ce, off);
    }
    if (k == 0) { consts[80] = cn; consts[81] = ce; }
}

// 4 lanes per node row: each lane loads 4 float4 (64 B), dot with its w
// chunk, 2-shuffle reduce. One wave covers 16 rows = 4 KiB. Direct grid.
__global__ __launch_bounds__(256)
void ga_node_att_kernel(const float* __restrict__ node_fts,
                        const int* __restrict__ seg_ids,
                        const float* __restrict__ consts,
                        float* __restrict__ out_e,      // d_out[0:N)
                        float* __restrict__ sums_node,  // ws, zeroed
                        int N) {
    const int gid = blockIdx.x * blockDim.x + threadIdx.x;
    const int row = gid >> 2;
    if (row >= N) return;
    const int lane4 = threadIdx.x & 3;

    const float4* wp = reinterpret_cast<const float4*>(&consts[lane4 * 16]);
    const float4 w0 = wp[0], w1 = wp[1], w2 = wp[2], w3 = wp[3];

    const float4* xp = reinterpret_cast<const float4*>(
        &node_fts[(size_t)row * 64 + lane4 * 16]);
    const float4 x0 = xp[0], x1 = xp[1], x2 = xp[2], x3 = xp[3];

    float d = x0.x * w0.x + x0.y * w0.y + x0.z * w0.z + x0.w * w0.w;
    d += x1.x * w1.x + x1.y * w1.y + x1.z * w1.z + x1.w * w1.w;
    d += x2.x * w2.x + x2.y * w2.y + x2.z * w2.z + x2.w * w2.w;
    d += x3.x * w3.x + x3.y * w3.y + x3.z * w3.z + x3.w * w3.w;
    d += __shfl_xor(d, 1);
    d += __shfl_xor(d, 2);

    if (lane4 == 0) {
        float att = consts[80] + d;
        att = att > 0.f ? att : ALPHA * att;     // leaky_relu
        att = fminf(fmaxf(att, -2.f), 2.f);      // clip
        const float e = __expf(att);
        out_e[row] = e;
        atomicAdd(&sums_node[seg_ids[row]], e);
    }
}

// 1 lane per edge row (16 floats = 4 float4 in-lane, no shuffles).
// One wave covers 64 rows = 4 KiB. Direct grid.
__global__ __launch_bounds__(256)
void ga_edge_att_kernel(const float* __restrict__ edges,
                        const int* __restrict__ seg_ids,
                        const float* __restrict__ consts,
                        float* __restrict__ out_e,      // d_out[N:2N)
                        float* __restrict__ sums_edge,  // ws, zeroed
                        int E) {
    const int row = blockIdx.x * blockDim.x + threadIdx.x;
    if (row >= E) return;

    const float4* wp = reinterpret_cast<const float4*>(&consts[64]);
    const float4 w0 = wp[0], w1 = wp[1], w2 = wp[2], w3 = wp[3];

    const float4* xp = reinterpret_cast<const float4*>(&edges[(size_t)row * 16]);
    const float4 x0 = xp[0], x1 = xp[1], x2 = xp[2], x3 = xp[3];

    float d = x0.x * w0.x + x0.y * w0.y + x0.z * w0.z + x0.w * w0.w;
    d += x1.x * w1.x + x1.y * w1.y + x1.z * w1.z + x1.w * w1.w;
    d += x2.x * w2.x + x2.y * w2.y + x2.z * w2.z + x2.w * w2.w;
    d += x3.x * w3.x + x3.y * w3.y + x3.z * w3.z + x3.w * w3.w;

    float att = consts[81] + d;
    att = att > 0.f ? att : ALPHA * att;
    att = fminf(fmaxf(att, -2.f), 2.f);
    const float e = __expf(att);
    out_e[row] = e;
    atomicAdd(&sums_edge[seg_ids[row]], e);
}

// Normalize both halves in place; 4 rows/thread vectorized.
__global__ __launch_bounds__(256)
void ga_norm_kernel(const int* __restrict__ seg_ids,
                    const float* __restrict__ sums_node,
                    const float* __restrict__ sums_edge,
                    float* __restrict__ out, int N) {
    const int q = blockIdx.x * blockDim.x + threadIdx.x;
    const int n4 = N >> 2;
    if (q < n4) {
        float* out2 = out + N;
        const int4 s = reinterpret_cast<const int4*>(seg_ids)[q];
        float4 o1 = reinterpret_cast<float4*>(out)[q];
        float4 o2 = reinterpret_cast<float4*>(out2)[q];
        o1.x /= sums_node[s.x]; o1.y /= sums_node[s.y];
        o1.z /= sums_node[s.z]; o1.w /= sums_node[s.w];
        o2.x /= sums_edge[s.x]; o2.y /= sums_edge[s.y];
        o2.z /= sums_edge[s.z]; o2.w /= sums_edge[s.w];
        reinterpret_cast<float4*>(out)[q] = o1;
        reinterpret_cast<float4*>(out2)[q] = o2;
    }
    // tail (N not divisible by 4): handled by the first threads of block 0
    const int tail_start = n4 << 2;
    const int j = tail_start + q;
    if (q < (N - tail_start)) {
        const int s = seg_ids[j];
        out[j]     /= sums_node[s];
        out[N + j] /= sums_edge[s];
    }
}

extern "C" void kernel_launch(void* const* d_in, const int* in_sizes, int n_in,
                              void* d_out, int out_size, void* d_ws, size_t ws_size,
                              hipStream_t stream) {
    const float* node_fts  = (const float*)d_in[0];
    // d_in[1] (edge_fts) is unused by the reference computation.
    const float* graph_fts = (const float*)d_in[2];
    const float* edges     = (const float*)d_in[3];
    const int*   seg_ids   = (const int*)  d_in[4];
    const float* W_node    = (const float*)d_in[5];
    const float* W_edge    = (const float*)d_in[6];
    const float* W_graph   = (const float*)d_in[7];
    const float* a_node    = (const float*)d_in[8];
    const float* a_edge    = (const float*)d_in[9];

    const int N = in_sizes[0] / 64;   // node rows
    const int E = in_sizes[4];        // edge rows == seg_ids count

    float* out       = (float*)d_out;
    float* sums_node = (float*)d_ws;        // [N]
    float* sums_edge = sums_node + N;       // [N]
    float* consts    = sums_edge + N;       // [96] (16B-aligned: 2N*4 % 16 == 0)

    hipMemsetAsync(d_ws, 0, (size_t)(2 * N) * sizeof(float), stream);

    ga_consts_kernel<<<1, 64, 0, stream>>>(graph_fts, W_node, W_edge, W_graph,
                                           a_node, a_edge, consts);

    const int node_blocks = (int)(((size_t)N * 4 + 255) / 256);
    ga_node_att_kernel<<<node_blocks, 256, 0, stream>>>(
        node_fts, seg_ids, consts, out, sums_node, N);

    const int edge_blocks = (E + 255) / 256;
    ga_edge_att_kernel<<<edge_blocks, 256, 0, stream>>>(
        edges, seg_ids, consts, out + N, sums_edge, E);

    const int norm_blocks = ((N >> 2) + 255) / 256;
    ga_norm_kernel<<<norm_blocks, 256, 0, stream>>>(seg_ids, sums_node,
                                                    sums_edge, out, N);
}